// Round 14
// baseline (242.557 us; speedup 1.0000x reference)
//
#include <hip/hip_runtime.h>
#include <cstdint>

// CTC loss, tf.nn.ctc_loss semantics (blank_index=0), B=1024 T=256 C=128 L=32.
// Round-22: grid-parallel stream (pre-committed from R21's null threshold).
// R21 showed DP is hidden; the ~62 us kernel is the softmax/stream at only
// 16 waves/CU with 32 barrier rounds. Split:
//   k1: 4096 blocks x 256 thr (16 blocks/CU -> full 32 waves/CU). Block
//       (b,q) streams 64 t-rows: zero inter-chunk barriers, depth-3 ring
//       (vmcnt(2) steady), LDS tile scatter, ONE barrier, coalesced uint4
//       dump to Gt[b][t][slot] (f16, log2-domain), partial S -> workspace.
//   k2: 1024 blocks x 64 thr (1 wave per b). 17x global_load_lds stages
//       Gt row-block (17.4 KB) to LDS; cmap/slotO recomputed in-registers
//       (ballot ranks == k1 compaction); R21 linear DP verbatim (register
//       handoff, 8-step exact-pow2 rescale) -> DP bit-matches R21.
// Numerics: Gc values/softmax identical; S reassociated q-major (R21
// proved epilogue-path changes pass). Fallback: R21 fused if ws too small.
// Predicted: k1 25-35 us, k2 6-10 us, dur 195.9 -> ~170-182.
// Pre-committed: dur >= 192 -> stream machinery is the floor.

#define CTC_BLANK 0
#define CTC_PAD   127
#define LOG2E     1.44269504088896340736f
#define LN2       0.69314718055994530942f

constexpr int Bn = 1024, Tn = 256, Cn = 128, Ln = 32;
constexpr int NSLOT = Ln + 1;     // 33 used slots
constexpr int GS    = 34;         // padded slot stride (f16)
constexpr int ROWB  = 64;         // t-rows per k1 block
constexpr int CR    = 8;          // rows per chunk
constexpr int NCHQ  = ROWB / CR;  // 8 chunks per k1 block
constexpr int GT_ROWBYTES = GS * 2;            // 68 B
constexpr int GT_BBYTES   = Tn * GT_ROWBYTES;  // 17408 B per b

constexpr size_t WS_GT   = 0;
constexpr size_t WS_PS   = (size_t)Bn * GT_BBYTES;          // 17,825,792
constexpr size_t WS_NEED = WS_PS + (size_t)Bn * 64 * 4;     // +262,144

__device__ __forceinline__ float fexp2(float x) { return __builtin_amdgcn_exp2f(x); }
__device__ __forceinline__ float flog2(float x) { return __builtin_amdgcn_logf(x); }

template <int CTRL>
__device__ __forceinline__ float dpp_add(float s) {
    int v = __builtin_amdgcn_update_dpp(0, __float_as_int(s), CTRL, 0xF, 0xF, true);
    return s + __int_as_float(v);
}
__device__ __forceinline__ float dpp_wave_shr1(float src, float old) {
    return __int_as_float(__builtin_amdgcn_update_dpp(
        __float_as_int(old), __float_as_int(src), 0x138, 0xF, 0xF, false));
}
__device__ __forceinline__ void gl_lds16(const float* g, float* l) {
    __builtin_amdgcn_global_load_lds(
        (const __attribute__((address_space(1))) uint32_t*)g,
        (__attribute__((address_space(3))) uint32_t*)l, 16, 0, 0);
}

// ---------------------------------------------------------------------------
// Kernel 1: stream softmax for rows [64q, 64q+64) of batch element b.
// ---------------------------------------------------------------------------
__global__ __launch_bounds__(256, 8) void ctc_softmax_kernel(
        const int*   __restrict__ y_true,   // [B, L]
        const float* __restrict__ y_pred,   // [B, T, C]
        _Float16*    __restrict__ Gt,       // [B][T][GS] log2-domain
        float*       __restrict__ psg)      // [B][4][16]
{
    __shared__ __align__(16) float raw[3][CR * Cn];   // 12 KB ring
    __shared__ __align__(16) _Float16 Gc64[ROWB * GS];// 4352 B tile
    __shared__ int labels[Ln];
    __shared__ __align__(16) int cmap[Cn];
    __shared__ int used[Cn];
    __shared__ int wcnt[4];

    const int idx  = blockIdx.x;
    const int b    = idx >> 2;
    const int q    = idx & 3;
    const int tid  = threadIdx.x;
    const int lane = tid & 63;
    const int wave = tid >> 6;          // 0..3
    const int half = lane >> 5;
    const int l32  = lane & 31;

    const float* gbase = y_pred + (size_t)b * Tn * Cn + (size_t)q * ROWB * Cn;

    // stage local chunk c (rows 8c+2w, 8c+2w+1): 1 KB per wave, ring slot c%3
    auto stage = [&](int c) {
        gl_lds16(gbase + (size_t)(c * CR + 2 * wave) * Cn + lane * 4,
                 &raw[c % 3][wave * 256]);
    };

    stage(0);
    stage(1);   // 2 chunks in flight; latency hides under the cmap build

    // ---- class->slot map (identical compaction to prior rounds) ----
    if (tid < Ln) labels[tid] = y_true[b * Ln + tid];
    if (tid < Cn) used[tid] = 0;
    __syncthreads();
    if (tid == 0) used[CTC_BLANK] = 1;
    if (tid < Ln) used[labels[tid]] = 1;
    __syncthreads();
    {
        bool f = (tid < Cn) && (used[tid] != 0);
        unsigned long long m = __ballot(f);
        if (lane == 0) wcnt[wave] = __popcll(m);
        __syncthreads();
        int base = 0;
        for (int w = 0; w < wave; ++w) base += wcnt[w];
        if (tid < Cn)
            cmap[tid] = f ? (base + __popcll(m & ((1ull << lane) - 1ull))) : -1;
        __syncthreads();   // drains prologue DMAs (chunks 0,1 landed)
    }

    const int4 cm = ((const int4*)cmap)[l32];
    const int rl = 2 * wave + half;     // row slot within chunk, 0..7
    float accE = 0.f, accO = 0.f;       // log2-domain partials (even/odd c)

    // ---- free-running stream: ZERO inter-chunk barriers ----
    for (int c = 0; c < NCHQ; ++c) {
        if (c < NCHQ - 2) stage(c + 2);
        __builtin_amdgcn_sched_barrier(0);
        if (c <= NCHQ - 3)      asm volatile("s_waitcnt vmcnt(2)" ::: "memory");
        else if (c == NCHQ - 2) asm volatile("s_waitcnt vmcnt(1)" ::: "memory");
        else                    asm volatile("s_waitcnt vmcnt(0)" ::: "memory");
        __builtin_amdgcn_sched_barrier(0);

        const int r = c * CR + rl;      // local row 0..63
        const float4 x = ((const float4*)&raw[c % 3][wave * 256 + half * 128])[l32];
        const float e0 = x.x * LOG2E, e1 = x.y * LOG2E,
                    e2 = x.z * LOG2E, e3 = x.w * LOG2E;
        if (cm.x >= 0) Gc64[r * GS + cm.x] = (_Float16)e0;
        if (cm.y >= 0) Gc64[r * GS + cm.y] = (_Float16)e1;
        if (cm.z >= 0) Gc64[r * GS + cm.z] = (_Float16)e2;
        if (cm.w >= 0) Gc64[r * GS + cm.w] = (_Float16)e3;
        float s = fexp2(e0) + fexp2(e1) + fexp2(e2) + fexp2(e3);
        s = dpp_add<0x111>(s);   // row_shr:1
        s = dpp_add<0x112>(s);   // row_shr:2
        s = dpp_add<0x114>(s);   // row_shr:4
        s = dpp_add<0x118>(s);   // row_shr:8
        s = dpp_add<0x142>(s);   // row_bcast:15
        if (c & 1) accO += flog2(s); else accE += flog2(s);  // lanes 31/63

        // retire this chunk's ds ops before its ring slot is re-staged
        asm volatile("s_waitcnt lgkmcnt(0)" ::: "memory");
    }
    if (l32 == 31) {
        psg[b * 64 + q * 16 + rl]     = accE;
        psg[b * 64 + q * 16 + rl + 8] = accO;
    }
    __syncthreads();   // publish Gc64

    // ---- coalesced dump: 4352 B = 272 uint4 ----
    {
        const uint4* src = (const uint4*)Gc64;
        uint4* dst = (uint4*)((char*)Gt + (size_t)b * GT_BBYTES + (size_t)q * ROWB * GT_ROWBYTES);
        dst[tid] = src[tid];
        if (tid < 16) dst[256 + tid] = src[256 + tid];
    }
}

// ---------------------------------------------------------------------------
// Kernel 2: linear-domain alpha DP, one wave per b. 1024 blocks x 64 thr.
// ---------------------------------------------------------------------------
__global__ __launch_bounds__(64) void ctc_dp_kernel(
        const int*      __restrict__ y_true,
        const _Float16* __restrict__ Gt,
        const float*    __restrict__ psg,
        float*          __restrict__ out)
{
    __shared__ __align__(16) _Float16 G[Tn * GS];   // 17408 B

    const int b = blockIdx.x;
    const int i = threadIdx.x;                      // lane 0..63

    // stage Gt[b] -> LDS: 17 x 1 KB direct-to-LDS
    #pragma unroll
    for (int j = 0; j < 17; ++j)
        gl_lds16((const float*)((const char*)Gt + (size_t)b * GT_BBYTES + j * 1024) + i * 4,
                 (float*)&G[j * 512]);

    // ---- recompute label constants in-registers (overlaps DMA) ----
    const int lr = (i < Ln) ? y_true[b * Ln + i] : CTC_PAD;  // own label
    bool u_lo = (i == CTC_BLANK);   // class i used?  (blank = class 0)
    bool u_hi = false;              // class i+64 used?
    #pragma unroll
    for (int j = 0; j < Ln; ++j) {
        const int lj = __shfl(lr, j, 64);
        u_lo |= (lj == i);
        u_hi |= (lj == i + 64);
    }
    const unsigned long long m0 = __ballot(u_lo);
    const unsigned long long m1 = __ballot(u_hi);
    const int nlo = __popcll(m0);
    auto rank = [&](int cls) -> int {   // == cmap[cls] of k1's compaction
        return (cls < 64)
            ? __popcll(m0 & ((1ull << cls) - 1ull))
            : nlo + __popcll(m1 & ((1ull << (cls - 64)) - 1ull));
    };
    const bool validO = (i < Ln);
    const bool validE = (i <= Ln);
    const int  myLab   = validO ? lr : -1;
    const int  prevLab = (i >= 1 && i < Ln) ? __shfl(lr, i - 1, 64) : -1;
    const int  slotO   = validO ? rank(lr) : 0;
    const bool skipO   = (i >= 1 && i < Ln) &&
                         (myLab != CTC_BLANK) && (myLab != prevLab);
    const int  len = __popcll(__ballot(validO && (myLab != CTC_PAD)));

    __builtin_amdgcn_sched_barrier(0);
    asm volatile("s_waitcnt vmcnt(0)" ::: "memory");   // LDS staged
    __builtin_amdgcn_sched_barrier(0);

    // ---- linear-domain DP, 8-step chunks with exact pow-2 rescale ----
    float aE = 0.f, aO = 0.f;
    int   Esc = 0;
    for (int tc = 0; tc < 32; ++tc) {
        const int t0 = tc * 8, t1 = t0 + 8;
        int t = t0;
        if (t == 0) {
            aE = (i == 0) ? fexp2((float)G[0])     : 0.f;
            aO = (i == 0) ? fexp2((float)G[slotO]) : 0.f;
            t = 1;
        }
        float pB[2], pO[2];
        const int ta = t, tb = (t + 1 < t1) ? t + 1 : t1 - 1;
        pB[0] = fexp2((float)G[ta * GS]);
        pO[0] = fexp2((float)G[ta * GS + slotO]);
        pB[1] = fexp2((float)G[tb * GS]);
        pO[1] = fexp2((float)G[tb * GS + slotO]);
        int k = 0;
        #pragma unroll 2
        for (; t < t1; ++t) {
            const float lpB = pB[k], lpO = pO[k];
            const int tp = (t + 2 < t1) ? t + 2 : t1 - 1;
            pB[k] = fexp2((float)G[tp * GS]);
            pO[k] = fexp2((float)G[tp * GS + slotO]);
            k ^= 1;
            const float aOup = dpp_wave_shr1(aO, 0.f);        // alpha[2i-1]
            const float nE = lpB * (aE + aOup);                       // 2i
            const float nO = lpO * (aO + aE + (skipO ? aOup : 0.f));  // 2i+1
            aE = validE ? nE : 0.f;
            aO = validO ? nO : 0.f;
        }
        float m = fmaxf(aE, aO);
        #pragma unroll
        for (int d = 1; d < 64; d <<= 1) m = fmaxf(m, __shfl_xor(m, d, 64));
        const int ex = ((__float_as_int(m) >> 23) & 255) - 127;
        const float sc = __int_as_float((127 - ex) << 23);    // 2^-ex exact
        aE *= sc; aO *= sc; Esc += ex;
    }

    const float v1 = __shfl(aE, len, 64);       // alpha[2*len]   (scaled)
    const float v2 = __shfl(aO, len - 1, 64);   // alpha[2*len-1] (scaled)
    if (i == 0) {
        float S = 0.f;
        const float4* ps = (const float4*)(psg + b * 64);
        #pragma unroll
        for (int j = 0; j < 16; ++j) {          // ascending flat order
            const float4 v = ps[j];
            S += v.x; S += v.y; S += v.z; S += v.w;
        }
        const float L2 = flog2(v1 + v2) + (float)Esc;
        out[b] = LN2 * (S - L2);
    }
}

// ---------------------------------------------------------------------------
// Fallback: R21 fused kernel (used only if ws_size < WS_NEED)
// ---------------------------------------------------------------------------
constexpr int FNCH = Tn / CR;   // 32

__global__ __launch_bounds__(256, 6) void ctc_fused_fallback(
        const int*   __restrict__ y_true,
        const float* __restrict__ y_pred,
        float*       __restrict__ out)
{
    __shared__ __align__(16) float raw[2][CR * Cn];
    __shared__ _Float16 Gc[Tn * NSLOT];
    __shared__ int   labels[Ln];
    __shared__ __align__(16) int cmap[Cn];
    __shared__ int   wcnt[4];
    __shared__ float partS[16];
    __shared__ float aEs[64], aOs[64];
    __shared__ int   EscS;
    int* const used = (int*)raw[1];

    const int b    = blockIdx.x;
    const int tid  = threadIdx.x;
    const int lane = tid & 63;
    const int wave = tid >> 6;
    const int half = lane >> 5;
    const int l32  = lane & 31;
    const int rotb = (b + (b >> 8)) & 3;

    const float* gbase = y_pred + (size_t)b * Tn * Cn;
    auto stage = [&](int c) {
        gl_lds16(gbase + (size_t)(c * CR + 2 * wave) * Cn + lane * 4,
                 &raw[c & 1][wave * 256]);
    };
    stage(0);

    if (tid < Ln) labels[tid] = y_true[b * Ln + tid];
    if (tid < Cn) used[tid] = 0;
    __syncthreads();
    if (tid == 0) used[CTC_BLANK] = 1;
    if (tid < Ln) used[labels[tid]] = 1;
    __syncthreads();
    {
        bool f = (tid < Cn) && (used[tid] != 0);
        unsigned long long m = __ballot(f);
        if (lane == 0) wcnt[wave] = __popcll(m);
        __syncthreads();
        int base = 0;
        for (int w = 0; w < wave; ++w) base += wcnt[w];
        if (tid < Cn)
            cmap[tid] = f ? (base + __popcll(m & ((1ull << lane) - 1ull))) : -1;
        __syncthreads();
    }

    const int4 cm = ((const int4*)cmap)[l32];
    const int rl = 2 * wave + half;
    float accE = 0.f, accO = 0.f;

    const int  i      = lane;
    const bool validO = (i < Ln);
    const bool validE = (i <= Ln);
    const int  myLab   = validO ? labels[i] : -1;
    const int  prevLab = (i >= 1 && i < Ln) ? labels[i - 1] : -1;
    const int  slotO   = validO ? cmap[myLab] : 0;
    const bool skipO   = (i >= 1 && i < Ln) &&
                         (myLab != CTC_BLANK) && (myLab != prevLab);
    const int  len = __popcll(__ballot(validO && (myLab != CTC_PAD)));
    float aE = 0.f, aO = 0.f;
    int   Esc = 0;

    auto dp_chunk = [&](int t0, int t1) {
        int t = t0;
        if (t == 0) {
            aE = (i == 0) ? fexp2((float)Gc[0])     : 0.f;
            aO = (i == 0) ? fexp2((float)Gc[slotO]) : 0.f;
            Esc = 0;
            t = 1;
        } else {
            aE = aEs[i]; aO = aOs[i]; Esc = EscS;
        }
        float pB[2], pO[2];
        const int ta = t, tb = (t + 1 < t1) ? t + 1 : t1 - 1;
        pB[0] = fexp2((float)Gc[ta * NSLOT]);
        pO[0] = fexp2((float)Gc[ta * NSLOT + slotO]);
        pB[1] = fexp2((float)Gc[tb * NSLOT]);
        pO[1] = fexp2((float)Gc[tb * NSLOT + slotO]);
        int k = 0;
        #pragma unroll 2
        for (; t < t1; ++t) {
            const float lpB = pB[k], lpO = pO[k];
            const int tp = (t + 2 < t1) ? t + 2 : t1 - 1;
            pB[k] = fexp2((float)Gc[tp * NSLOT]);
            pO[k] = fexp2((float)Gc[tp * NSLOT + slotO]);
            k ^= 1;
            const float aOup = dpp_wave_shr1(aO, 0.f);
            const float nE = lpB * (aE + aOup);
            const float nO = lpO * (aO + aE + (skipO ? aOup : 0.f));
            aE = validE ? nE : 0.f;
            aO = validO ? nO : 0.f;
        }
        float m = fmaxf(aE, aO);
        #pragma unroll
        for (int d = 1; d < 64; d <<= 1) m = fmaxf(m, __shfl_xor(m, d, 64));
        const int ex = ((__float_as_int(m) >> 23) & 255) - 127;
        const float sc = __int_as_float((127 - ex) << 23);
        aE *= sc; aO *= sc; Esc += ex;
        aEs[i] = aE; aOs[i] = aO;
        if (i == 0) EscS = Esc;
    };

    auto process = [&](int c, float& acc) {
        const int r = c * CR + rl;
        const float4 x = ((const float4*)&raw[c & 1][wave * 256 + half * 128])[l32];
        const float e0 = x.x * LOG2E, e1 = x.y * LOG2E,
                    e2 = x.z * LOG2E, e3 = x.w * LOG2E;
        if (cm.x >= 0) Gc[r * NSLOT + cm.x] = (_Float16)e0;
        if (cm.y >= 0) Gc[r * NSLOT + cm.y] = (_Float16)e1;
        if (cm.z >= 0) Gc[r * NSLOT + cm.z] = (_Float16)e2;
        if (cm.w >= 0) Gc[r * NSLOT + cm.w] = (_Float16)e3;
        float s = fexp2(e0) + fexp2(e1) + fexp2(e2) + fexp2(e3);
        s = dpp_add<0x111>(s);
        s = dpp_add<0x112>(s);
        s = dpp_add<0x114>(s);
        s = dpp_add<0x118>(s);
        s = dpp_add<0x142>(s);
        acc += flog2(s);
    };

    auto iter = [&](int c, float& acc) {
        if (c + 1 < FNCH) stage(c + 1);
        if (c > 0 && wave == ((c - 1 + rotb) & 3))
            dp_chunk((c - 1) * CR, c * CR);
        __builtin_amdgcn_sched_barrier(0);
        if (c + 1 < FNCH) asm volatile("s_waitcnt vmcnt(1)" ::: "memory");
        else              asm volatile("s_waitcnt vmcnt(0)" ::: "memory");
        __builtin_amdgcn_sched_barrier(0);
        process(c, acc);
        if (c == FNCH - 1 && l32 == 31) {
            partS[rl] = accE; partS[rl + 8] = accO;
        }
        asm volatile("s_waitcnt lgkmcnt(0)" ::: "memory");
        __builtin_amdgcn_s_barrier();
    };

    for (int cc = 0; cc < FNCH / 2; ++cc) {
        iter(2 * cc, accE);
        iter(2 * cc + 1, accO);
    }

    if (wave == ((FNCH - 1 + rotb) & 3)) {
        dp_chunk(Tn - CR, Tn);
        const float v1 = __shfl(aE, len, 64);
        const float v2 = __shfl(aO, len - 1, 64);
        if (i == 0) {
            float S = 0.f;
            #pragma unroll
            for (int j = 0; j < 16; ++j) S += partS[j];
            const float L2 = flog2(v1 + v2) + (float)Esc;
            out[b] = LN2 * (S - L2);
        }
    }
}

extern "C" void kernel_launch(void* const* d_in, const int* in_sizes, int n_in,
                              void* d_out, int out_size, void* d_ws, size_t ws_size,
                              hipStream_t stream) {
    const int*   y_true = (const int*)d_in[0];
    const float* y_pred = (const float*)d_in[1];
    float*       out    = (float*)d_out;
    if (d_ws != nullptr && ws_size >= WS_NEED) {
        _Float16* Gt = (_Float16*)((char*)d_ws + WS_GT);
        float*    ps = (float*)((char*)d_ws + WS_PS);
        ctc_softmax_kernel<<<Bn * 4, 256, 0, stream>>>(y_true, y_pred, Gt, ps);
        ctc_dp_kernel<<<Bn, 64, 0, stream>>>(y_true, Gt, ps, out);
    } else {
        ctc_fused_fallback<<<Bn, 256, 0, stream>>>(y_true, y_pred, out);
    }
}